// Round 4
// baseline (369.359 us; speedup 1.0000x reference)
//
#include <hip/hip_runtime.h>

typedef unsigned short u16;
typedef unsigned int u32;
typedef __attribute__((ext_vector_type(8))) short short8;
typedef __attribute__((ext_vector_type(4))) float f32x4;
typedef __attribute__((ext_vector_type(2))) float f32x2;
typedef __attribute__((ext_vector_type(8))) unsigned short ushort8_t;

#define SEQ 2048
#define DIM 1024
#define DINNER 2048
#define NPROJ 33
#define NPROJ_PAD 48
#define LC 16   // chunk length
#define NC 128  // SEQ / LC

__device__ __forceinline__ u16 f2bf(float f) {
  union { float f; u32 u; } v; v.f = f;
  u32 r = (v.u + 0x7fffu + ((v.u >> 16) & 1u)) >> 16;
  return (u16)r;
}
__device__ __forceinline__ float bf2f(u16 s) {
  union { u32 u; float f; } v; v.u = ((u32)s) << 16;
  return v.f;
}
__device__ __forceinline__ float lo_bf(u32 w) {
  union { u32 u; float f; } v; v.u = w << 16; return v.f;
}
__device__ __forceinline__ float hi_bf(u32 w) {
  union { u32 u; float f; } v; v.u = w & 0xffff0000u; return v.f;
}
__device__ __forceinline__ float fexp2(float x) {
#if __has_builtin(__builtin_amdgcn_exp2f)
  return __builtin_amdgcn_exp2f(x);
#else
  return __expf(x * 0.69314718f);
#endif
}
__device__ __forceinline__ float frcp(float x) {
#if __has_builtin(__builtin_amdgcn_rcpf)
  return __builtin_amdgcn_rcpf(x);
#else
  return 1.f / x;
#endif
}
__device__ __forceinline__ float softplus(float x) {
  return fmaxf(x, 0.f) + __logf(1.f + __expf(-fabsf(x)));
}
__device__ __forceinline__ f32x2 sp2(float v) { f32x2 r; r.x = v; r.y = v; return r; }
__device__ __forceinline__ f32x2 pkfma(f32x2 a, f32x2 b, f32x2 c) {
  return __builtin_elementwise_fma(a, b, c);
}
__device__ __forceinline__ void async16(const void* g, void* l) {
  __builtin_amdgcn_global_load_lds(
      (const __attribute__((address_space(1))) u32*)g,
      (__attribute__((address_space(3))) u32*)l, 16, 0, 0);
}

// ---------------- cast kernels ----------------
__global__ void cast_w_kernel(const float* __restrict__ w1, const float* __restrict__ w3,
                              u16* __restrict__ o1, u16* __restrict__ o3) {
  int i = blockIdx.x * 256 + threadIdx.x;  // 524288
  float4 a = ((const float4*)w1)[i];
  float4 b = ((const float4*)w3)[i];
  ushort4 oa, ob;
  oa.x = f2bf(a.x); oa.y = f2bf(a.y); oa.z = f2bf(a.z); oa.w = f2bf(a.w);
  ob.x = f2bf(b.x); ob.y = f2bf(b.y); ob.z = f2bf(b.z); ob.w = f2bf(b.w);
  ((ushort4*)o1)[i] = oa;
  ((ushort4*)o3)[i] = ob;
}

// padded x_proj rows REORDERED: B -> 0..15, C -> 16..31, dt -> 32, zero 33..47.
// (B/C rows then sit at 16B-aligned uniform addresses in proj for s_load.)
__global__ void cast_w2pad_kernel(const float* __restrict__ src, u16* __restrict__ dst) {
  int i = blockIdx.x * 256 + threadIdx.x;  // 48*2048
  int j = i >> 11, k = i & 2047;
  u16 v;
  if (j < 32) v = f2bf(src[(1 + j) * 2048 + k]);       // B (src 1..16), C (src 17..32)
  else if (j == 32) v = f2bf(src[k]);                  // dt (src row 0)
  else v = (u16)0;
  dst[i] = v;
}

// A2 paired fold: A2[(d>>1)*32 + n*2 + (d&1)] = -exp(A_log[d][n]) * log2(e)
__global__ void foldA_kernel(const float* __restrict__ A_log, float* __restrict__ A2) {
  int i = blockIdx.x * 256 + threadIdx.x;  // 32768
  int p = i >> 5, n2 = i & 31;
  int d = p * 2 + (n2 & 1), n = n2 >> 1;
  A2[i] = -__expf(A_log[d * 16 + n]) * 1.44269504f;
}

// ---------------- layernorm (row=1024) -> bf16 ----------------
__global__ __launch_bounds__(256) void ln_kernel(const float* __restrict__ x,
                                                 const float* __restrict__ w,
                                                 const float* __restrict__ b,
                                                 u16* __restrict__ h) {
  const int row = blockIdx.x;
  const int tid = threadIdx.x;
  const int lane = tid & 63, wave = tid >> 6;
  const float4 v = ((const float4*)(x + (size_t)row * DIM))[tid];
  float s = v.x + v.y + v.z + v.w;
  float q = v.x * v.x + v.y * v.y + v.z * v.z + v.w * v.w;
  for (int off = 32; off; off >>= 1) {
    s += __shfl_down(s, off);
    q += __shfl_down(q, off);
  }
  __shared__ float sbuf[8];
  if (lane == 0) { sbuf[wave] = s; sbuf[4 + wave] = q; }
  __syncthreads();
  float tot = sbuf[0] + sbuf[1] + sbuf[2] + sbuf[3];
  float totq = sbuf[4] + sbuf[5] + sbuf[6] + sbuf[7];
  const float mean = tot * (1.0f / DIM);
  const float var = totq * (1.0f / DIM) - mean * mean;
  const float rs = rsqrtf(var + 1e-5f);
  const float4 wv = ((const float4*)w)[tid];
  const float4 bv = ((const float4*)b)[tid];
  ushort4 o;
  o.x = f2bf((v.x - mean) * rs * wv.x + bv.x);
  o.y = f2bf((v.y - mean) * rs * wv.y + bv.y);
  o.z = f2bf((v.z - mean) * rs * wv.z + bv.z);
  o.w = f2bf((v.w - mean) * rs * wv.w + bv.w);
  ((ushort4*)(h + (size_t)row * DIM))[tid] = o;
}

// ---------------- bf16 GEMM, B^T input, 128x128 tile, 512 thr (8 waves) ----------------
__global__ __launch_bounds__(512) void gemm_bf16_kernel(const u16* __restrict__ A,
                                                        const u16* __restrict__ Bt,
                                                        u16* __restrict__ C,
                                                        int K, int N) {
  __shared__ u16 As[128 * 32];
  __shared__ u16 Bs[128 * 32];
  const int tid = threadIdx.x;
  const int lane = tid & 63, wave = tid >> 6;
  const int wm = wave >> 2, wn = wave & 3;
  const int row16 = lane & 15, quad = lane >> 4;
  const int flat = blockIdx.x + gridDim.x * blockIdx.y;
  const int xcd = flat & 7;
  const int sidx = flat >> 3;
  const int bm = xcd * 8 + (sidx & 7);   // 64 bm panels, 8 per XCD
  const int bn = sidx >> 3;
  f32x4 acc[4][2] = {};
  const u16* Ablk = A + (size_t)bm * 128 * K;
  const u16* Bblk = Bt + (size_t)bn * 128 * K;
  const int r = tid >> 2, cc = (tid & 3) * 8;
  for (int k0 = 0; k0 < K; k0 += 32) {
    async16(Ablk + (size_t)r * K + k0 + cc, &As[tid * 8]);
    async16(Bblk + (size_t)r * K + k0 + cc, &Bs[tid * 8]);
    __syncthreads();
    short8 af[4], bfr[2];
#pragma unroll
    for (int i = 0; i < 4; ++i)
      af[i] = *(const short8*)&As[(wm * 64 + i * 16 + row16) * 32 + quad * 8];
#pragma unroll
    for (int j = 0; j < 2; ++j)
      bfr[j] = *(const short8*)&Bs[(wn * 32 + j * 16 + row16) * 32 + quad * 8];
#pragma unroll
    for (int i = 0; i < 4; ++i)
#pragma unroll
      for (int j = 0; j < 2; ++j)
        acc[i][j] = __builtin_amdgcn_mfma_f32_16x16x32_bf16(af[i], bfr[j], acc[i][j], 0, 0, 0);
    __syncthreads();
  }
#pragma unroll
  for (int i = 0; i < 4; ++i) {
    int m = bm * 128 + wm * 64 + i * 16 + quad * 4;
#pragma unroll
    for (int j = 0; j < 2; ++j) {
      int n = bn * 128 + wn * 32 + j * 16 + row16;
#pragma unroll
      for (int rr = 0; rr < 4; ++rr)
        C[(size_t)(m + rr) * N + n] = f2bf(acc[i][j][rr]);
    }
  }
}

// ---------------- out GEMM: fp32 out + residual, 512 thr, XCD swizzle ----------------
__global__ __launch_bounds__(512) void gemm_out_kernel(const u16* __restrict__ A,
                                                       const u16* __restrict__ Bt,
                                                       const float* __restrict__ resid,
                                                       float* __restrict__ C,
                                                       int K, int N) {
  __shared__ u16 As[128 * 32];
  __shared__ u16 Bs[128 * 32];
  const int tid = threadIdx.x;
  const int lane = tid & 63, wave = tid >> 6;
  const int wm = wave >> 2, wn = wave & 3;
  const int row16 = lane & 15, quad = lane >> 4;
  const int flat = blockIdx.x + gridDim.x * blockIdx.y;
  const int xcd = flat & 7;
  const int sidx = flat >> 3;
  const int bm = xcd * 8 + (sidx & 7);
  const int bn = sidx >> 3;
  f32x4 acc[4][2] = {};
  const u16* Ablk = A + (size_t)bm * 128 * K;
  const u16* Bblk = Bt + (size_t)bn * 128 * K;
  const int r = tid >> 2, cc = (tid & 3) * 8;
  for (int k0 = 0; k0 < K; k0 += 32) {
    async16(Ablk + (size_t)r * K + k0 + cc, &As[tid * 8]);
    async16(Bblk + (size_t)r * K + k0 + cc, &Bs[tid * 8]);
    __syncthreads();
    short8 af[4], bfr[2];
#pragma unroll
    for (int i = 0; i < 4; ++i)
      af[i] = *(const short8*)&As[(wm * 64 + i * 16 + row16) * 32 + quad * 8];
#pragma unroll
    for (int j = 0; j < 2; ++j)
      bfr[j] = *(const short8*)&Bs[(wn * 32 + j * 16 + row16) * 32 + quad * 8];
#pragma unroll
    for (int i = 0; i < 4; ++i)
#pragma unroll
      for (int j = 0; j < 2; ++j)
        acc[i][j] = __builtin_amdgcn_mfma_f32_16x16x32_bf16(af[i], bfr[j], acc[i][j], 0, 0, 0);
    __syncthreads();
  }
#pragma unroll
  for (int i = 0; i < 4; ++i) {
    int m = bm * 128 + wm * 64 + i * 16 + quad * 4;
#pragma unroll
    for (int j = 0; j < 2; ++j) {
      int n = bn * 128 + wn * 32 + j * 16 + row16;
#pragma unroll
      for (int rr = 0; rr < 4; ++rr) {
        size_t idx = (size_t)(m + rr) * N + n;
        C[idx] = acc[i][j][rr] + resid[idx];
      }
    }
  }
}

// ---------------- causal depthwise conv (k=4) + SiLU, vectorized ----------------
__global__ __launch_bounds__(256) void conv_silu_kernel(const u16* __restrict__ c1,
                                                        const float* __restrict__ cw,
                                                        u16* __restrict__ cs) {
  const int tid = threadIdx.x;
  const int dg = tid * 8;
  const size_t m0 = (size_t)blockIdx.x * 8;
  const int l0 = (int)(m0 & (SEQ - 1));
  float w[4][8];
  {
    const float4* cw4 = (const float4*)(cw + (size_t)dg * 4);
#pragma unroll
    for (int c = 0; c < 8; ++c) {
      float4 v = cw4[c];
      w[0][c] = v.x; w[1][c] = v.y; w[2][c] = v.z; w[3][c] = v.w;
    }
  }
  const u16* base = c1 + m0 * DINNER + dg;
  ushort8_t win0, win1, win2, win3;
  const ushort8_t zero = (ushort8_t)0;
  if (l0 == 0) {
    win0 = zero; win1 = zero; win2 = zero;
  } else {
    win0 = *(const ushort8_t*)(base - 3 * DINNER);
    win1 = *(const ushort8_t*)(base - 2 * DINNER);
    win2 = *(const ushort8_t*)(base - 1 * DINNER);
  }
  win3 = *(const ushort8_t*)(base);
#pragma unroll
  for (int t = 0; t < 8; ++t) {
    ushort8_t nxt = win3;
    if (t < 7) nxt = *(const ushort8_t*)(base + (size_t)(t + 1) * DINNER);
    ushort8_t o;
#pragma unroll
    for (int c = 0; c < 8; ++c) {
      float acc = bf2f((u16)win0[c]) * w[0][c];
      acc = fmaf(bf2f((u16)win1[c]), w[1][c], acc);
      acc = fmaf(bf2f((u16)win2[c]), w[2][c], acc);
      acc = fmaf(bf2f((u16)win3[c]), w[3][c], acc);
      const float s = acc * frcp(1.f + __expf(-acc));
      o[c] = (unsigned short)f2bf(s);
    }
    *(ushort8_t*)(cs + (m0 + t) * DINNER + dg) = o;
    win0 = win1; win1 = win2; win2 = win3; win3 = nxt;
  }
}

// ---------------- x_proj GEMM: M-tile 32, N=48(pad), K=2048; grid 256 ----------------
__global__ __launch_bounds__(128) void gemm_w2_kernel(const u16* __restrict__ A,
                                                      const u16* __restrict__ Bt,
                                                      float* __restrict__ C) {
  __shared__ u16 As[32 * 32];
  __shared__ u16 Bs[48 * 32];
  const int tid = threadIdx.x;
  const int lane = tid & 63, wave = tid >> 6;   // 2 waves
  const int row16 = lane & 15, quad = lane >> 4;
  const int bm = blockIdx.x;
  const int K = DINNER;
  f32x4 acc[3] = {};
  const u16* Ablk = A + (size_t)bm * 32 * K;
  const int r = tid >> 2, cc = (tid & 3) * 8;   // r in [0,32)
  for (int k0 = 0; k0 < K; k0 += 32) {
    async16(Ablk + (size_t)r * K + k0 + cc, &As[tid * 8]);
    async16(Bt + (size_t)r * K + k0 + cc, &Bs[tid * 8]);        // B rows 0..31
    if (tid < 64)
      async16(Bt + (size_t)(32 + r) * K + k0 + cc, &Bs[1024 + tid * 8]);  // rows 32..47
    __syncthreads();
    short8 af = *(const short8*)&As[(wave * 16 + row16) * 32 + quad * 8];
    short8 bfr[3];
#pragma unroll
    for (int j = 0; j < 3; ++j)
      bfr[j] = *(const short8*)&Bs[(j * 16 + row16) * 32 + quad * 8];
#pragma unroll
    for (int j = 0; j < 3; ++j)
      acc[j] = __builtin_amdgcn_mfma_f32_16x16x32_bf16(af, bfr[j], acc[j], 0, 0, 0);
    __syncthreads();
  }
  const int m = bm * 32 + wave * 16 + quad * 4;
#pragma unroll
  for (int j = 0; j < 3; ++j) {
    const int n = j * 16 + row16;
#pragma unroll
    for (int rr = 0; rr < 4; ++rr)
      C[(size_t)(m + rr) * NPROJ_PAD + n] = acc[j][rr];
  }
}

// ======================= chunked selective scan =======================
// 1 thread = 2 adjacent channels (packed f32x2). NO LDS: B/C/dt rows of proj
// are wave-uniform -> scalar loads (SGPR operands); A2 pre-folded.
// grid phase1/3: (DINNER/512, NC, B) = (4,128,4) = 2048 blocks x 4 waves.
// S layout: [b][c][d][16] bf16 (32 MB, aliased onto d_out's out region,
// fully overwritten by gemm_out at the end); Tdt: [b][c][d] fp32.

// ---- phase 1: local scan (init 0) -> S_loc (bf16), Tdt ----
__global__ __launch_bounds__(256) void scan_phase1(const float* __restrict__ proj,
                                                   const u16* __restrict__ xs,
                                                   const float* __restrict__ dtw_,
                                                   const float* __restrict__ dtb_,
                                                   const float* __restrict__ A2,
                                                   u16* __restrict__ S,
                                                   float* __restrict__ Tdt) {
  const int tid = threadIdx.x;
  const int d0 = blockIdx.x * 512 + tid * 2;
  const int c = blockIdx.y;
  const int b = blockIdx.z;
  const size_t mrow = (size_t)b * SEQ + c * LC;
  f32x2 An2[16];
  {
    const float4* Ap = (const float4*)(A2 + (size_t)(d0 >> 1) * 32);
#pragma unroll
    for (int q = 0; q < 8; ++q) {
      float4 v = Ap[q];
      An2[2 * q].x = v.x;     An2[2 * q].y = v.y;
      An2[2 * q + 1].x = v.z; An2[2 * q + 1].y = v.w;
    }
  }
  const float2 dtwv = *(const float2*)(dtw_ + d0);
  const float2 dtbv = *(const float2*)(dtb_ + d0);
  f32x2 dtw2; dtw2.x = dtwv.x; dtw2.y = dtwv.y;
  f32x2 dtb2; dtb2.x = dtbv.x; dtb2.y = dtbv.y;
  f32x2 s[16];
#pragma unroll
  for (int n = 0; n < 16; ++n) s[n] = sp2(0.f);
  f32x2 Tsum = sp2(0.f);
  const float* pr = proj + mrow * NPROJ_PAD;   // wave-uniform
  const u16* xp = xs + mrow * DINNER + d0;
  u32 xw = *(const u32*)xp;
#pragma unroll 2
  for (int t = 0; t < LC; ++t) {
    f32x2 xv; xv.x = lo_bf(xw); xv.y = hi_bf(xw);
    if (t + 1 < LC) xw = *(const u32*)(xp + (size_t)(t + 1) * DINNER);
    const float dtin = pr[32];
    f32x2 dtv = pkfma(sp2(dtin), dtw2, dtb2);
    f32x2 sp; sp.x = softplus(dtv.x); sp.y = softplus(dtv.y);
    Tsum += sp;
    const float4* Br = (const float4*)pr;      // B at cols 0..15 (16B-aligned)
#pragma unroll
    for (int q = 0; q < 4; ++q) {
      const float4 Bq = Br[q];
      const float bqa[4] = {Bq.x, Bq.y, Bq.z, Bq.w};
#pragma unroll
      for (int j = 0; j < 4; ++j) {
        const int n = q * 4 + j;
        f32x2 e = An2[n] * sp;
        f32x2 dk; dk.x = fexp2(e.x); dk.y = fexp2(e.y);
        s[n] = pkfma(dk, s[n], sp2(bqa[j]) * xv);
      }
    }
    pr += NPROJ_PAD;
  }
  const size_t so = ((size_t)(b * NC + c) * DINNER + d0) * 16;
  ushort8_t o0, o1, o2, o3;
#pragma unroll
  for (int j = 0; j < 8; ++j) {
    o0[j] = f2bf(s[j].x);     o1[j] = f2bf(s[8 + j].x);
    o2[j] = f2bf(s[j].y);     o3[j] = f2bf(s[8 + j].y);
  }
  *(ushort8_t*)(S + so) = o0;       *(ushort8_t*)(S + so + 8) = o1;
  *(ushort8_t*)(S + so + 16) = o2;  *(ushort8_t*)(S + so + 24) = o3;
  *(float2*)(Tdt + (size_t)(b * NC + c) * DINNER + d0) = make_float2(Tsum.x, Tsum.y);
}

// ---- phase 2: cross-chunk combine; S becomes per-chunk INIT state ----
// one thread per (b,d,n) element: 131072 threads; NC=128 serial iterations
__global__ __launch_bounds__(256) void scan_phase2(const float* __restrict__ A2,
                                                   u16* __restrict__ S,
                                                   const float* __restrict__ Tdt,
                                                   float* __restrict__ out_state) {
  const int idx = blockIdx.x * 256 + threadIdx.x;  // B*DINNER*16
  const int n = idx & 15;
  const int d = (idx >> 4) & (DINNER - 1);
  const int b = idx >> 15;
  const float An = A2[((d >> 1) << 5) + (n << 1) + (d & 1)];
  float prev = 0.f;
#pragma unroll 4
  for (int c = 0; c < NC; ++c) {
    const size_t base = (size_t)(b * NC + c) * DINNER + d;
    const float T = Tdt[base];
    const size_t so = base * 16 + n;
    const float loc = bf2f(S[so]);
    S[so] = f2bf(prev);
    prev = fmaf(fexp2(An * T), prev, loc);
  }
  out_state[((size_t)b * DINNER + d) * 16 + n] = prev;
}

// ---- phase 3: re-scan chunk from init state, emit silu(y) ----
__global__ __launch_bounds__(256) void scan_phase3(const float* __restrict__ proj,
                                                   const u16* __restrict__ xs,
                                                   const float* __restrict__ dtw_,
                                                   const float* __restrict__ dtb_,
                                                   const float* __restrict__ A2,
                                                   const float* __restrict__ Dp,
                                                   const u16* __restrict__ S,
                                                   u16* __restrict__ ysil) {
  const int tid = threadIdx.x;
  const int d0 = blockIdx.x * 512 + tid * 2;
  const int c = blockIdx.y;
  const int b = blockIdx.z;
  const size_t mrow = (size_t)b * SEQ + c * LC;
  f32x2 An2[16];
  {
    const float4* Ap = (const float4*)(A2 + (size_t)(d0 >> 1) * 32);
#pragma unroll
    for (int q = 0; q < 8; ++q) {
      float4 v = Ap[q];
      An2[2 * q].x = v.x;     An2[2 * q].y = v.y;
      An2[2 * q + 1].x = v.z; An2[2 * q + 1].y = v.w;
    }
  }
  const float2 dtwv = *(const float2*)(dtw_ + d0);
  const float2 dtbv = *(const float2*)(dtb_ + d0);
  const float2 Ddv = *(const float2*)(Dp + d0);
  f32x2 dtw2; dtw2.x = dtwv.x; dtw2.y = dtwv.y;
  f32x2 dtb2; dtb2.x = dtbv.x; dtb2.y = dtbv.y;
  f32x2 Dd2; Dd2.x = Ddv.x; Dd2.y = Ddv.y;
  f32x2 s[16];
  const size_t so = ((size_t)(b * NC + c) * DINNER + d0) * 16;
  {
    ushort8_t v0 = *(const ushort8_t*)(S + so);
    ushort8_t v1 = *(const ushort8_t*)(S + so + 8);
    ushort8_t v2 = *(const ushort8_t*)(S + so + 16);
    ushort8_t v3 = *(const ushort8_t*)(S + so + 24);
#pragma unroll
    for (int j = 0; j < 8; ++j) {
      s[j].x = bf2f((u16)v0[j]);     s[8 + j].x = bf2f((u16)v1[j]);
      s[j].y = bf2f((u16)v2[j]);     s[8 + j].y = bf2f((u16)v3[j]);
    }
  }
  const float* pr = proj + mrow * NPROJ_PAD;   // wave-uniform
  const u16* xp = xs + mrow * DINNER + d0;
  u16* yp = ysil + mrow * DINNER + d0;
  u32 xw = *(const u32*)xp;
#pragma unroll 2
  for (int t = 0; t < LC; ++t) {
    f32x2 xv; xv.x = lo_bf(xw); xv.y = hi_bf(xw);
    if (t + 1 < LC) xw = *(const u32*)(xp + (size_t)(t + 1) * DINNER);
    const float dtin = pr[32];
    f32x2 dtv = pkfma(sp2(dtin), dtw2, dtb2);
    f32x2 sp; sp.x = softplus(dtv.x); sp.y = softplus(dtv.y);
    f32x2 y = Dd2 * xv;
    const float4* Br = (const float4*)pr;          // B cols 0..15
    const float4* Cr = (const float4*)(pr + 16);   // C cols 16..31
#pragma unroll
    for (int q = 0; q < 4; ++q) {
      const float4 Bq = Br[q];
      const float4 Cq = Cr[q];
      const float bqa[4] = {Bq.x, Bq.y, Bq.z, Bq.w};
      const float cqa[4] = {Cq.x, Cq.y, Cq.z, Cq.w};
#pragma unroll
      for (int j = 0; j < 4; ++j) {
        const int n = q * 4 + j;
        f32x2 e = An2[n] * sp;
        f32x2 dk; dk.x = fexp2(e.x); dk.y = fexp2(e.y);
        s[n] = pkfma(dk, s[n], sp2(bqa[j]) * xv);
        y = pkfma(sp2(cqa[j]), s[n], y);
      }
    }
    const float sy0 = y.x * frcp(1.f + __expf(-y.x));
    const float sy1 = y.y * frcp(1.f + __expf(-y.y));
    const u32 ow = (u32)f2bf(sy0) | ((u32)f2bf(sy1) << 16);
    *(u32*)(yp + (size_t)t * DINNER) = ow;
    pr += NPROJ_PAD;
  }
}

// ---------------- launch ----------------
extern "C" void kernel_launch(void* const* d_in, const int* in_sizes, int n_in,
                              void* d_out, int out_size, void* d_ws, size_t ws_size,
                              hipStream_t stream) {
  const float* x = (const float*)d_in[0];
  const float* in_proj_w = (const float*)d_in[1];
  const float* conv_w = (const float*)d_in[2];
  const float* x_proj_w = (const float*)d_in[3];
  const float* dt_proj_w = (const float*)d_in[4];
  const float* dt_proj_b = (const float*)d_in[5];
  const float* A_log = (const float*)d_in[6];
  const float* Dvec = (const float*)d_in[7];
  const float* out_proj_w = (const float*)d_in[8];
  const float* norm_w = (const float*)d_in[9];
  const float* norm_b = (const float*)d_in[10];

  char* ws = (char*)d_ws;
  u16* h = (u16*)(ws + 0);                    // 8192x1024 bf16 (16 MB)
  u16* w1b = (u16*)(ws + 16777216);           // 2048x1024 bf16 (4 MB)
  u16* w3b = (u16*)(ws + 20971520);           // 1024x2048 bf16 (4 MB)
  u16* w2b = (u16*)(ws + 25165824);           // 48x2048 bf16 (0.19 MB)
  u16* c1 = (u16*)(ws + 25362432);            // 8192x2048 bf16 (32 MB)
  u16* ysil = c1;                             // aliased: c1 dead after conv
  u16* cs = (u16*)(ws + 58916864);            // 8192x2048 bf16 (32 MB)
  float* proj = (float*)(ws + 92471296);      // 8192x48 fp32 (1.5 MB)
  float* Tdt = (float*)(ws + 94044160);       // [b][c][d] fp32, NC=128 (4 MB)
  float* A2 = (float*)(ws + 98238464);        // paired A fold (128 KB)

  float* out = (float*)d_out;
  float* out_state = out + (size_t)4 * SEQ * DIM;
  // Sbuf (32 MB, [b][c][d][16] bf16) aliased onto the `out` region of d_out:
  // written by phase1/2, read by phase3; gemm_out fully overwrites `out`
  // afterwards, so final output is untouched. out_state lives beyond it.
  u16* Sbuf = (u16*)d_out;

  cast_w_kernel<<<2048, 256, 0, stream>>>(in_proj_w, out_proj_w, w1b, w3b);
  cast_w2pad_kernel<<<384, 256, 0, stream>>>(x_proj_w, w2b);
  foldA_kernel<<<128, 256, 0, stream>>>(A_log, A2);
  ln_kernel<<<8192, 256, 0, stream>>>(x, norm_w, norm_b, h);
  gemm_bf16_kernel<<<dim3(DINNER / 128, 64), 512, 0, stream>>>(h, w1b, c1, DIM, DINNER);
  conv_silu_kernel<<<1024, 256, 0, stream>>>(c1, conv_w, cs);
  gemm_w2_kernel<<<256, 128, 0, stream>>>(cs, w2b, proj);
  scan_phase1<<<dim3(DINNER / 512, NC, 4), 256, 0, stream>>>(proj, cs, dt_proj_w, dt_proj_b,
                                                             A2, Sbuf, Tdt);
  scan_phase2<<<512, 256, 0, stream>>>(A2, Sbuf, Tdt, out_state);
  scan_phase3<<<dim3(DINNER / 512, NC, 4), 256, 0, stream>>>(proj, cs, dt_proj_w, dt_proj_b,
                                                             A2, Dvec, Sbuf, ysil);
  gemm_out_kernel<<<dim3(DIM / 128, 64), 512, 0, stream>>>(ysil, w3b, x, out, DINNER, DIM);
}

// Round 5
// 358.851 us; speedup vs baseline: 1.0293x; 1.0293x over previous
//
#include <hip/hip_runtime.h>

typedef unsigned short u16;
typedef unsigned int u32;
typedef __attribute__((ext_vector_type(8))) short short8;
typedef __attribute__((ext_vector_type(4))) float f32x4;
typedef __attribute__((ext_vector_type(2))) float f32x2;
typedef __attribute__((ext_vector_type(8))) unsigned short ushort8_t;

#define SEQ 2048
#define DIM 1024
#define DINNER 2048
#define NPROJ 33
#define NPROJ_PAD 48
#define LC 16   // chunk length
#define NC 128  // SEQ / LC

__device__ __forceinline__ u16 f2bf(float f) {
  union { float f; u32 u; } v; v.f = f;
  u32 r = (v.u + 0x7fffu + ((v.u >> 16) & 1u)) >> 16;
  return (u16)r;
}
__device__ __forceinline__ float bf2f(u16 s) {
  union { u32 u; float f; } v; v.u = ((u32)s) << 16;
  return v.f;
}
__device__ __forceinline__ float lo_bf(u32 w) {
  union { u32 u; float f; } v; v.u = w << 16; return v.f;
}
__device__ __forceinline__ float hi_bf(u32 w) {
  union { u32 u; float f; } v; v.u = w & 0xffff0000u; return v.f;
}
// packed f32x2 -> 2x bf16 in one u32 (RNE, matches f2bf). gfx950 has no
// builtin for v_cvt_pk_bf16_f32 (guide T12) -> inline asm.
__device__ __forceinline__ u32 pkbf(float a, float b) {
  u32 r;
  asm("v_cvt_pk_bf16_f32 %0, %1, %2" : "=v"(r) : "v"(a), "v"(b));
  return r;
}
__device__ __forceinline__ float fexp2(float x) {
#if __has_builtin(__builtin_amdgcn_exp2f)
  return __builtin_amdgcn_exp2f(x);
#else
  return __expf(x * 0.69314718f);
#endif
}
__device__ __forceinline__ float frcp(float x) {
#if __has_builtin(__builtin_amdgcn_rcpf)
  return __builtin_amdgcn_rcpf(x);
#else
  return 1.f / x;
#endif
}
__device__ __forceinline__ float softplus(float x) {
  return fmaxf(x, 0.f) + __logf(1.f + __expf(-fabsf(x)));
}
__device__ __forceinline__ f32x2 sp2(float v) { f32x2 r; r.x = v; r.y = v; return r; }
__device__ __forceinline__ f32x2 pkfma(f32x2 a, f32x2 b, f32x2 c) {
  return __builtin_elementwise_fma(a, b, c);
}
__device__ __forceinline__ void async16(const void* g, void* l) {
  __builtin_amdgcn_global_load_lds(
      (const __attribute__((address_space(1))) u32*)g,
      (__attribute__((address_space(3))) u32*)l, 16, 0, 0);
}

// ---------------- merged prep: weight casts + x_proj reorder + A fold ----------------
// blocks [0,2048): cast in_proj/out_proj to bf16
// blocks [2048,2432): x_proj pad+reorder (B->0..15, C->16..31, dt->32)
// blocks [2432,2560): A2 fold
__global__ __launch_bounds__(256) void prep_kernel(const float* __restrict__ w1,
                                                   const float* __restrict__ w3,
                                                   const float* __restrict__ xpw,
                                                   const float* __restrict__ A_log,
                                                   u16* __restrict__ o1,
                                                   u16* __restrict__ o3,
                                                   u16* __restrict__ w2b,
                                                   float* __restrict__ A2) {
  const int gb = blockIdx.x;
  const int tid = threadIdx.x;
  if (gb < 2048) {
    int i = gb * 256 + tid;  // 524288
    float4 a = ((const float4*)w1)[i];
    float4 b = ((const float4*)w3)[i];
    ushort4 oa, ob;
    oa.x = f2bf(a.x); oa.y = f2bf(a.y); oa.z = f2bf(a.z); oa.w = f2bf(a.w);
    ob.x = f2bf(b.x); ob.y = f2bf(b.y); ob.z = f2bf(b.z); ob.w = f2bf(b.w);
    ((ushort4*)o1)[i] = oa;
    ((ushort4*)o3)[i] = ob;
  } else if (gb < 2432) {
    int i = (gb - 2048) * 256 + tid;  // 48*2048
    int j = i >> 11, k = i & 2047;
    u16 v;
    if (j < 32) v = f2bf(xpw[(1 + j) * 2048 + k]);   // B (src 1..16), C (src 17..32)
    else if (j == 32) v = f2bf(xpw[k]);              // dt (src row 0)
    else v = (u16)0;
    w2b[i] = v;
  } else {
    int i = (gb - 2432) * 256 + tid;  // 32768
    int p = i >> 5, n2 = i & 31;
    int d = p * 2 + (n2 & 1), n = n2 >> 1;
    A2[i] = -__expf(A_log[d * 16 + n]) * 1.44269504f;
  }
}

// ---------------- layernorm (row=1024) -> bf16 ----------------
__global__ __launch_bounds__(256) void ln_kernel(const float* __restrict__ x,
                                                 const float* __restrict__ w,
                                                 const float* __restrict__ b,
                                                 u16* __restrict__ h) {
  const int row = blockIdx.x;
  const int tid = threadIdx.x;
  const int lane = tid & 63, wave = tid >> 6;
  const float4 v = ((const float4*)(x + (size_t)row * DIM))[tid];
  float s = v.x + v.y + v.z + v.w;
  float q = v.x * v.x + v.y * v.y + v.z * v.z + v.w * v.w;
  for (int off = 32; off; off >>= 1) {
    s += __shfl_down(s, off);
    q += __shfl_down(q, off);
  }
  __shared__ float sbuf[8];
  if (lane == 0) { sbuf[wave] = s; sbuf[4 + wave] = q; }
  __syncthreads();
  float tot = sbuf[0] + sbuf[1] + sbuf[2] + sbuf[3];
  float totq = sbuf[4] + sbuf[5] + sbuf[6] + sbuf[7];
  const float mean = tot * (1.0f / DIM);
  const float var = totq * (1.0f / DIM) - mean * mean;
  const float rs = rsqrtf(var + 1e-5f);
  const float4 wv = ((const float4*)w)[tid];
  const float4 bv = ((const float4*)b)[tid];
  ushort4 o;
  o.x = f2bf((v.x - mean) * rs * wv.x + bv.x);
  o.y = f2bf((v.y - mean) * rs * wv.y + bv.y);
  o.z = f2bf((v.z - mean) * rs * wv.z + bv.z);
  o.w = f2bf((v.w - mean) * rs * wv.w + bv.w);
  ((ushort4*)(h + (size_t)row * DIM))[tid] = o;
}

// ---------------- bf16 GEMM, B^T input, 128x128 tile, 512 thr (8 waves) ----------------
__global__ __launch_bounds__(512) void gemm_bf16_kernel(const u16* __restrict__ A,
                                                        const u16* __restrict__ Bt,
                                                        u16* __restrict__ C,
                                                        int K, int N) {
  __shared__ u16 As[128 * 32];
  __shared__ u16 Bs[128 * 32];
  const int tid = threadIdx.x;
  const int lane = tid & 63, wave = tid >> 6;
  const int wm = wave >> 2, wn = wave & 3;
  const int row16 = lane & 15, quad = lane >> 4;
  const int flat = blockIdx.x + gridDim.x * blockIdx.y;
  const int xcd = flat & 7;
  const int sidx = flat >> 3;
  const int bm = xcd * 8 + (sidx & 7);   // 64 bm panels, 8 per XCD
  const int bn = sidx >> 3;
  f32x4 acc[4][2] = {};
  const u16* Ablk = A + (size_t)bm * 128 * K;
  const u16* Bblk = Bt + (size_t)bn * 128 * K;
  const int r = tid >> 2, cc = (tid & 3) * 8;
  for (int k0 = 0; k0 < K; k0 += 32) {
    async16(Ablk + (size_t)r * K + k0 + cc, &As[tid * 8]);
    async16(Bblk + (size_t)r * K + k0 + cc, &Bs[tid * 8]);
    __syncthreads();
    short8 af[4], bfr[2];
#pragma unroll
    for (int i = 0; i < 4; ++i)
      af[i] = *(const short8*)&As[(wm * 64 + i * 16 + row16) * 32 + quad * 8];
#pragma unroll
    for (int j = 0; j < 2; ++j)
      bfr[j] = *(const short8*)&Bs[(wn * 32 + j * 16 + row16) * 32 + quad * 8];
#pragma unroll
    for (int i = 0; i < 4; ++i)
#pragma unroll
      for (int j = 0; j < 2; ++j)
        acc[i][j] = __builtin_amdgcn_mfma_f32_16x16x32_bf16(af[i], bfr[j], acc[i][j], 0, 0, 0);
    __syncthreads();
  }
#pragma unroll
  for (int i = 0; i < 4; ++i) {
    int m = bm * 128 + wm * 64 + i * 16 + quad * 4;
#pragma unroll
    for (int j = 0; j < 2; ++j) {
      int n = bn * 128 + wn * 32 + j * 16 + row16;
#pragma unroll
      for (int rr = 0; rr < 4; ++rr)
        C[(size_t)(m + rr) * N + n] = f2bf(acc[i][j][rr]);
    }
  }
}

// ---------------- out GEMM: fp32 out + residual, 512 thr, XCD swizzle ----------------
__global__ __launch_bounds__(512) void gemm_out_kernel(const u16* __restrict__ A,
                                                       const u16* __restrict__ Bt,
                                                       const float* __restrict__ resid,
                                                       float* __restrict__ C,
                                                       int K, int N) {
  __shared__ u16 As[128 * 32];
  __shared__ u16 Bs[128 * 32];
  const int tid = threadIdx.x;
  const int lane = tid & 63, wave = tid >> 6;
  const int wm = wave >> 2, wn = wave & 3;
  const int row16 = lane & 15, quad = lane >> 4;
  const int flat = blockIdx.x + gridDim.x * blockIdx.y;
  const int xcd = flat & 7;
  const int sidx = flat >> 3;
  const int bm = xcd * 8 + (sidx & 7);
  const int bn = sidx >> 3;
  f32x4 acc[4][2] = {};
  const u16* Ablk = A + (size_t)bm * 128 * K;
  const u16* Bblk = Bt + (size_t)bn * 128 * K;
  const int r = tid >> 2, cc = (tid & 3) * 8;
  for (int k0 = 0; k0 < K; k0 += 32) {
    async16(Ablk + (size_t)r * K + k0 + cc, &As[tid * 8]);
    async16(Bblk + (size_t)r * K + k0 + cc, &Bs[tid * 8]);
    __syncthreads();
    short8 af[4], bfr[2];
#pragma unroll
    for (int i = 0; i < 4; ++i)
      af[i] = *(const short8*)&As[(wm * 64 + i * 16 + row16) * 32 + quad * 8];
#pragma unroll
    for (int j = 0; j < 2; ++j)
      bfr[j] = *(const short8*)&Bs[(wn * 32 + j * 16 + row16) * 32 + quad * 8];
#pragma unroll
    for (int i = 0; i < 4; ++i)
#pragma unroll
      for (int j = 0; j < 2; ++j)
        acc[i][j] = __builtin_amdgcn_mfma_f32_16x16x32_bf16(af[i], bfr[j], acc[i][j], 0, 0, 0);
    __syncthreads();
  }
#pragma unroll
  for (int i = 0; i < 4; ++i) {
    int m = bm * 128 + wm * 64 + i * 16 + quad * 4;
#pragma unroll
    for (int j = 0; j < 2; ++j) {
      int n = bn * 128 + wn * 32 + j * 16 + row16;
#pragma unroll
      for (int rr = 0; rr < 4; ++rr) {
        size_t idx = (size_t)(m + rr) * N + n;
        C[idx] = acc[i][j][rr] + resid[idx];
      }
    }
  }
}

// ---------------- causal depthwise conv (k=4) + SiLU, vectorized ----------------
__global__ __launch_bounds__(256) void conv_silu_kernel(const u16* __restrict__ c1,
                                                        const float* __restrict__ cw,
                                                        u16* __restrict__ cs) {
  const int tid = threadIdx.x;
  const int dg = tid * 8;
  const size_t m0 = (size_t)blockIdx.x * 8;
  const int l0 = (int)(m0 & (SEQ - 1));
  float w[4][8];
  {
    const float4* cw4 = (const float4*)(cw + (size_t)dg * 4);
#pragma unroll
    for (int c = 0; c < 8; ++c) {
      float4 v = cw4[c];
      w[0][c] = v.x; w[1][c] = v.y; w[2][c] = v.z; w[3][c] = v.w;
    }
  }
  const u16* base = c1 + m0 * DINNER + dg;
  ushort8_t win0, win1, win2, win3;
  const ushort8_t zero = (ushort8_t)0;
  if (l0 == 0) {
    win0 = zero; win1 = zero; win2 = zero;
  } else {
    win0 = *(const ushort8_t*)(base - 3 * DINNER);
    win1 = *(const ushort8_t*)(base - 2 * DINNER);
    win2 = *(const ushort8_t*)(base - 1 * DINNER);
  }
  win3 = *(const ushort8_t*)(base);
#pragma unroll
  for (int t = 0; t < 8; ++t) {
    ushort8_t nxt = win3;
    if (t < 7) nxt = *(const ushort8_t*)(base + (size_t)(t + 1) * DINNER);
    ushort8_t o;
#pragma unroll
    for (int c = 0; c < 8; ++c) {
      float acc = bf2f((u16)win0[c]) * w[0][c];
      acc = fmaf(bf2f((u16)win1[c]), w[1][c], acc);
      acc = fmaf(bf2f((u16)win2[c]), w[2][c], acc);
      acc = fmaf(bf2f((u16)win3[c]), w[3][c], acc);
      const float s = acc * frcp(1.f + __expf(-acc));
      o[c] = (unsigned short)f2bf(s);
    }
    *(ushort8_t*)(cs + (m0 + t) * DINNER + dg) = o;
    win0 = win1; win1 = win2; win2 = win3; win3 = nxt;
  }
}

// ---------------- x_proj GEMM: M-tile 32, N=48(pad), K=2048; grid 256 ----------------
__global__ __launch_bounds__(128) void gemm_w2_kernel(const u16* __restrict__ A,
                                                      const u16* __restrict__ Bt,
                                                      float* __restrict__ C) {
  __shared__ u16 As[32 * 32];
  __shared__ u16 Bs[48 * 32];
  const int tid = threadIdx.x;
  const int lane = tid & 63, wave = tid >> 6;   // 2 waves
  const int row16 = lane & 15, quad = lane >> 4;
  const int bm = blockIdx.x;
  const int K = DINNER;
  f32x4 acc[3] = {};
  const u16* Ablk = A + (size_t)bm * 32 * K;
  const int r = tid >> 2, cc = (tid & 3) * 8;   // r in [0,32)
  for (int k0 = 0; k0 < K; k0 += 32) {
    async16(Ablk + (size_t)r * K + k0 + cc, &As[tid * 8]);
    async16(Bt + (size_t)r * K + k0 + cc, &Bs[tid * 8]);        // B rows 0..31
    if (tid < 64)
      async16(Bt + (size_t)(32 + r) * K + k0 + cc, &Bs[1024 + tid * 8]);  // rows 32..47
    __syncthreads();
    short8 af = *(const short8*)&As[(wave * 16 + row16) * 32 + quad * 8];
    short8 bfr[3];
#pragma unroll
    for (int j = 0; j < 3; ++j)
      bfr[j] = *(const short8*)&Bs[(j * 16 + row16) * 32 + quad * 8];
#pragma unroll
    for (int j = 0; j < 3; ++j)
      acc[j] = __builtin_amdgcn_mfma_f32_16x16x32_bf16(af, bfr[j], acc[j], 0, 0, 0);
    __syncthreads();
  }
  const int m = bm * 32 + wave * 16 + quad * 4;
#pragma unroll
  for (int j = 0; j < 3; ++j) {
    const int n = j * 16 + row16;
#pragma unroll
    for (int rr = 0; rr < 4; ++rr)
      C[(size_t)(m + rr) * NPROJ_PAD + n] = acc[j][rr];
  }
}

// ======================= chunked selective scan =======================
// 1 thread = 2 adjacent channels (packed f32x2). NO LDS: B/C/dt rows of proj
// are wave-uniform -> scalar loads (SGPR operands); A2 pre-folded.
// grid phase1/3: (DINNER/512, NC, B) = (4,128,4) = 2048 blocks x 4 waves.
// S layout: [b][c][d][16] bf16 (32 MB, aliased onto d_out's out region,
// fully overwritten by gemm_out at the end); Tdt: [b][c][d] fp32.

// ---- phase 1: local scan (init 0) -> S_loc (bf16), Tdt ----
__global__ __launch_bounds__(256) void scan_phase1(const float* __restrict__ proj,
                                                   const u16* __restrict__ xs,
                                                   const float* __restrict__ dtw_,
                                                   const float* __restrict__ dtb_,
                                                   const float* __restrict__ A2,
                                                   u16* __restrict__ S,
                                                   float* __restrict__ Tdt) {
  const int tid = threadIdx.x;
  const int d0 = blockIdx.x * 512 + tid * 2;
  const int c = blockIdx.y;
  const int b = blockIdx.z;
  const size_t mrow = (size_t)b * SEQ + c * LC;
  f32x2 An2[16];
  {
    const float4* Ap = (const float4*)(A2 + (size_t)(d0 >> 1) * 32);
#pragma unroll
    for (int q = 0; q < 8; ++q) {
      float4 v = Ap[q];
      An2[2 * q].x = v.x;     An2[2 * q].y = v.y;
      An2[2 * q + 1].x = v.z; An2[2 * q + 1].y = v.w;
    }
  }
  const float2 dtwv = *(const float2*)(dtw_ + d0);
  const float2 dtbv = *(const float2*)(dtb_ + d0);
  f32x2 dtw2; dtw2.x = dtwv.x; dtw2.y = dtwv.y;
  f32x2 dtb2; dtb2.x = dtbv.x; dtb2.y = dtbv.y;
  f32x2 s[16];
#pragma unroll
  for (int n = 0; n < 16; ++n) s[n] = sp2(0.f);
  f32x2 Tsum = sp2(0.f);
  const float* pr = proj + mrow * NPROJ_PAD;   // wave-uniform
  const u16* xp = xs + mrow * DINNER + d0;
  u32 xw = *(const u32*)xp;
#pragma unroll 4
  for (int t = 0; t < LC; ++t) {
    f32x2 xv; xv.x = lo_bf(xw); xv.y = hi_bf(xw);
    if (t + 1 < LC) xw = *(const u32*)(xp + (size_t)(t + 1) * DINNER);
    const float dtin = pr[32];
    f32x2 dtv = pkfma(sp2(dtin), dtw2, dtb2);
    f32x2 sp; sp.x = softplus(dtv.x); sp.y = softplus(dtv.y);
    Tsum += sp;
    const float4* Br = (const float4*)pr;      // B at cols 0..15 (16B-aligned)
#pragma unroll
    for (int q = 0; q < 4; ++q) {
      const float4 Bq = Br[q];
      const float bqa[4] = {Bq.x, Bq.y, Bq.z, Bq.w};
#pragma unroll
      for (int j = 0; j < 4; ++j) {
        const int n = q * 4 + j;
        f32x2 e = An2[n] * sp;
        f32x2 dk; dk.x = fexp2(e.x); dk.y = fexp2(e.y);
        s[n] = pkfma(dk, s[n], sp2(bqa[j]) * xv);
      }
    }
    pr += NPROJ_PAD;
  }
  const size_t so = ((size_t)(b * NC + c) * DINNER + d0) * 16;
  uint4 w0, w1, w2, w3;
  w0.x = pkbf(s[0].x, s[1].x);   w0.y = pkbf(s[2].x, s[3].x);
  w0.z = pkbf(s[4].x, s[5].x);   w0.w = pkbf(s[6].x, s[7].x);
  w1.x = pkbf(s[8].x, s[9].x);   w1.y = pkbf(s[10].x, s[11].x);
  w1.z = pkbf(s[12].x, s[13].x); w1.w = pkbf(s[14].x, s[15].x);
  w2.x = pkbf(s[0].y, s[1].y);   w2.y = pkbf(s[2].y, s[3].y);
  w2.z = pkbf(s[4].y, s[5].y);   w2.w = pkbf(s[6].y, s[7].y);
  w3.x = pkbf(s[8].y, s[9].y);   w3.y = pkbf(s[10].y, s[11].y);
  w3.z = pkbf(s[12].y, s[13].y); w3.w = pkbf(s[14].y, s[15].y);
  *(uint4*)(S + so) = w0;        *(uint4*)(S + so + 8) = w1;
  *(uint4*)(S + so + 16) = w2;   *(uint4*)(S + so + 24) = w3;
  *(float2*)(Tdt + (size_t)(b * NC + c) * DINNER + d0) = make_float2(Tsum.x, Tsum.y);
}

// ---- phase 2: cross-chunk combine; S becomes per-chunk INIT state ----
// one thread per (b,d,n) element: 131072 threads; NC=128 serial iterations
__global__ __launch_bounds__(256) void scan_phase2(const float* __restrict__ A2,
                                                   u16* __restrict__ S,
                                                   const float* __restrict__ Tdt,
                                                   float* __restrict__ out_state) {
  const int idx = blockIdx.x * 256 + threadIdx.x;  // B*DINNER*16
  const int n = idx & 15;
  const int d = (idx >> 4) & (DINNER - 1);
  const int b = idx >> 15;
  const float An = A2[((d >> 1) << 5) + (n << 1) + (d & 1)];
  float prev = 0.f;
#pragma unroll 4
  for (int c = 0; c < NC; ++c) {
    const size_t base = (size_t)(b * NC + c) * DINNER + d;
    const float T = Tdt[base];
    const size_t so = base * 16 + n;
    const float loc = bf2f(S[so]);
    S[so] = f2bf(prev);
    prev = fmaf(fexp2(An * T), prev, loc);
  }
  out_state[((size_t)b * DINNER + d) * 16 + n] = prev;
}

// ---- phase 3: re-scan chunk from init state, emit silu(y) ----
__global__ __launch_bounds__(256) void scan_phase3(const float* __restrict__ proj,
                                                   const u16* __restrict__ xs,
                                                   const float* __restrict__ dtw_,
                                                   const float* __restrict__ dtb_,
                                                   const float* __restrict__ A2,
                                                   const float* __restrict__ Dp,
                                                   const u16* __restrict__ S,
                                                   u16* __restrict__ ysil) {
  const int tid = threadIdx.x;
  const int d0 = blockIdx.x * 512 + tid * 2;
  const int c = blockIdx.y;
  const int b = blockIdx.z;
  const size_t mrow = (size_t)b * SEQ + c * LC;
  f32x2 An2[16];
  {
    const float4* Ap = (const float4*)(A2 + (size_t)(d0 >> 1) * 32);
#pragma unroll
    for (int q = 0; q < 8; ++q) {
      float4 v = Ap[q];
      An2[2 * q].x = v.x;     An2[2 * q].y = v.y;
      An2[2 * q + 1].x = v.z; An2[2 * q + 1].y = v.w;
    }
  }
  const float2 dtwv = *(const float2*)(dtw_ + d0);
  const float2 dtbv = *(const float2*)(dtb_ + d0);
  const float2 Ddv = *(const float2*)(Dp + d0);
  f32x2 dtw2; dtw2.x = dtwv.x; dtw2.y = dtwv.y;
  f32x2 dtb2; dtb2.x = dtbv.x; dtb2.y = dtbv.y;
  f32x2 Dd2; Dd2.x = Ddv.x; Dd2.y = Ddv.y;
  f32x2 s[16];
  const size_t so = ((size_t)(b * NC + c) * DINNER + d0) * 16;
  {
    uint4 v0 = *(const uint4*)(S + so);
    uint4 v1 = *(const uint4*)(S + so + 8);
    uint4 v2 = *(const uint4*)(S + so + 16);
    uint4 v3 = *(const uint4*)(S + so + 24);
    const u32 a0[4] = {v0.x, v0.y, v0.z, v0.w};
    const u32 a1[4] = {v1.x, v1.y, v1.z, v1.w};
    const u32 a2[4] = {v2.x, v2.y, v2.z, v2.w};
    const u32 a3[4] = {v3.x, v3.y, v3.z, v3.w};
#pragma unroll
    for (int j = 0; j < 4; ++j) {
      s[2 * j].x = lo_bf(a0[j]);     s[2 * j + 1].x = hi_bf(a0[j]);
      s[8 + 2 * j].x = lo_bf(a1[j]); s[8 + 2 * j + 1].x = hi_bf(a1[j]);
      s[2 * j].y = lo_bf(a2[j]);     s[2 * j + 1].y = hi_bf(a2[j]);
      s[8 + 2 * j].y = lo_bf(a3[j]); s[8 + 2 * j + 1].y = hi_bf(a3[j]);
    }
  }
  const float* pr = proj + mrow * NPROJ_PAD;   // wave-uniform
  const u16* xp = xs + mrow * DINNER + d0;
  u16* yp = ysil + mrow * DINNER + d0;
  u32 xw = *(const u32*)xp;
#pragma unroll 4
  for (int t = 0; t < LC; ++t) {
    f32x2 xv; xv.x = lo_bf(xw); xv.y = hi_bf(xw);
    if (t + 1 < LC) xw = *(const u32*)(xp + (size_t)(t + 1) * DINNER);
    const float dtin = pr[32];
    f32x2 dtv = pkfma(sp2(dtin), dtw2, dtb2);
    f32x2 sp; sp.x = softplus(dtv.x); sp.y = softplus(dtv.y);
    // 4 independent y accumulators: break the 16-deep serial fma chain
    f32x2 ya[4];
    ya[0] = Dd2 * xv; ya[1] = sp2(0.f); ya[2] = sp2(0.f); ya[3] = sp2(0.f);
    const float4* Br = (const float4*)pr;          // B cols 0..15
    const float4* Cr = (const float4*)(pr + 16);   // C cols 16..31
#pragma unroll
    for (int q = 0; q < 4; ++q) {
      const float4 Bq = Br[q];
      const float4 Cq = Cr[q];
      const float bqa[4] = {Bq.x, Bq.y, Bq.z, Bq.w};
      const float cqa[4] = {Cq.x, Cq.y, Cq.z, Cq.w};
#pragma unroll
      for (int j = 0; j < 4; ++j) {
        const int n = q * 4 + j;
        f32x2 e = An2[n] * sp;
        f32x2 dk; dk.x = fexp2(e.x); dk.y = fexp2(e.y);
        s[n] = pkfma(dk, s[n], sp2(bqa[j]) * xv);
        ya[q] = pkfma(sp2(cqa[j]), s[n], ya[q]);
      }
    }
    f32x2 y = (ya[0] + ya[1]) + (ya[2] + ya[3]);
    const float sy0 = y.x * frcp(1.f + __expf(-y.x));
    const float sy1 = y.y * frcp(1.f + __expf(-y.y));
    *(u32*)(yp + (size_t)t * DINNER) = pkbf(sy0, sy1);
    pr += NPROJ_PAD;
  }
}

// ---------------- launch ----------------
extern "C" void kernel_launch(void* const* d_in, const int* in_sizes, int n_in,
                              void* d_out, int out_size, void* d_ws, size_t ws_size,
                              hipStream_t stream) {
  const float* x = (const float*)d_in[0];
  const float* in_proj_w = (const float*)d_in[1];
  const float* conv_w = (const float*)d_in[2];
  const float* x_proj_w = (const float*)d_in[3];
  const float* dt_proj_w = (const float*)d_in[4];
  const float* dt_proj_b = (const float*)d_in[5];
  const float* A_log = (const float*)d_in[6];
  const float* Dvec = (const float*)d_in[7];
  const float* out_proj_w = (const float*)d_in[8];
  const float* norm_w = (const float*)d_in[9];
  const float* norm_b = (const float*)d_in[10];

  char* ws = (char*)d_ws;
  u16* h = (u16*)(ws + 0);                    // 8192x1024 bf16 (16 MB)
  u16* w1b = (u16*)(ws + 16777216);           // 2048x1024 bf16 (4 MB)
  u16* w3b = (u16*)(ws + 20971520);           // 1024x2048 bf16 (4 MB)
  u16* w2b = (u16*)(ws + 25165824);           // 48x2048 bf16 (0.19 MB)
  u16* c1 = (u16*)(ws + 25362432);            // 8192x2048 bf16 (32 MB)
  u16* ysil = c1;                             // aliased: c1 dead after conv
  u16* cs = (u16*)(ws + 58916864);            // 8192x2048 bf16 (32 MB)
  float* proj = (float*)(ws + 92471296);      // 8192x48 fp32 (1.5 MB)
  float* Tdt = (float*)(ws + 94044160);       // [b][c][d] fp32, NC=128 (4 MB)
  float* A2 = (float*)(ws + 98238464);        // paired A fold (128 KB)

  float* out = (float*)d_out;
  float* out_state = out + (size_t)4 * SEQ * DIM;
  // Sbuf (32 MB, [b][c][d][16] bf16) aliased onto the `out` region of d_out:
  // written by phase1/2, read by phase3; gemm_out fully overwrites `out`
  // afterwards, so final output is untouched. out_state lives beyond it.
  u16* Sbuf = (u16*)d_out;

  prep_kernel<<<2560, 256, 0, stream>>>(in_proj_w, out_proj_w, x_proj_w, A_log,
                                        w1b, w3b, w2b, A2);
  ln_kernel<<<8192, 256, 0, stream>>>(x, norm_w, norm_b, h);
  gemm_bf16_kernel<<<dim3(DINNER / 128, 64), 512, 0, stream>>>(h, w1b, c1, DIM, DINNER);
  conv_silu_kernel<<<1024, 256, 0, stream>>>(c1, conv_w, cs);
  gemm_w2_kernel<<<256, 128, 0, stream>>>(cs, w2b, proj);
  scan_phase1<<<dim3(DINNER / 512, NC, 4), 256, 0, stream>>>(proj, cs, dt_proj_w, dt_proj_b,
                                                             A2, Sbuf, Tdt);
  scan_phase2<<<512, 256, 0, stream>>>(A2, Sbuf, Tdt, out_state);
  scan_phase3<<<dim3(DINNER / 512, NC, 4), 256, 0, stream>>>(proj, cs, dt_proj_w, dt_proj_b,
                                                             A2, Dvec, Sbuf, ysil);
  gemm_out_kernel<<<dim3(DIM / 128, 64), 512, 0, stream>>>(ysil, w3b, x, out, DINNER, DIM);
}